// Round 1
// baseline (216.757 us; speedup 1.0000x reference)
//
#include <hip/hip_runtime.h>

// StochasticPool2D eval-mode: out = sum(w^2)/sum(w) over non-overlapping 2x2
// windows of relu(x); windows summing to 0 produce 0.
// x: [64, 256, 112, 112] f32  ->  out: [64, 256, 56, 56] f32
//
// Memory-bound: 822 MB read + 205 MB write, zero reuse. Each thread handles
// 4 consecutive input columns across a row pair (2 outputs): two float4 loads
// + one float2 store, fully coalesced.

#define W_IN   112
#define WO     56
#define HO     56
#define WP     28          // Wo/2 = float4-pairs per output row
#define PLANE  (112 * 112) // input elems per (b,c) plane
#define OPLANE (56 * 56)   // output elems per (b,c) plane

__global__ __launch_bounds__(256) void stoch_pool2d_kernel(
    const float* __restrict__ in, float* __restrict__ out, unsigned int npairs) {
    unsigned int stride = gridDim.x * blockDim.x;
    for (unsigned int p = blockIdx.x * blockDim.x + threadIdx.x; p < npairs;
         p += stride) {
        unsigned int wp   = p % WP;          // which float4 group in the row
        unsigned int rest = p / WP;
        unsigned int ho   = rest % HO;       // output row
        unsigned int bc   = rest / HO;       // fused batch*channel plane

        unsigned int ibase = bc * PLANE + (2u * ho) * W_IN + wp * 4u;
        float4 r0 = *reinterpret_cast<const float4*>(in + ibase);
        float4 r1 = *reinterpret_cast<const float4*>(in + ibase + W_IN);

        float a0 = fmaxf(r0.x, 0.f), a1 = fmaxf(r0.y, 0.f);
        float a2 = fmaxf(r0.z, 0.f), a3 = fmaxf(r0.w, 0.f);
        float b0 = fmaxf(r1.x, 0.f), b1 = fmaxf(r1.y, 0.f);
        float b2 = fmaxf(r1.z, 0.f), b3 = fmaxf(r1.w, 0.f);

        float s0 = (a0 + a1) + (b0 + b1);
        float q0 = (a0 * a0 + a1 * a1) + (b0 * b0 + b1 * b1);
        float s1 = (a2 + a3) + (b2 + b3);
        float q1 = (a2 * a2 + a3 * a3) + (b2 * b2 + b3 * b3);

        float o0 = (s0 > 0.f) ? (q0 / s0) : 0.f;
        float o1 = (s1 > 0.f) ? (q1 / s1) : 0.f;

        unsigned int obase = bc * OPLANE + ho * WO + wp * 2u;
        *reinterpret_cast<float2*>(out + obase) = make_float2(o0, o1);
    }
}

extern "C" void kernel_launch(void* const* d_in, const int* in_sizes, int n_in,
                              void* d_out, int out_size, void* d_ws, size_t ws_size,
                              hipStream_t stream) {
    const float* x = (const float*)d_in[0];
    float* out = (float*)d_out;

    // total input elems = B*C*H*W; pairs = output elems / 2
    unsigned int npairs = (unsigned int)((long long)in_sizes[0] / 8);

    const int block = 256;
    const int grid = 2048;  // 256 CUs * 8 blocks/CU; grid-stride covers the rest
    stoch_pool2d_kernel<<<grid, block, 0, stream>>>(x, out, npairs);
}

// Round 3
// 205.351 us; speedup vs baseline: 1.0555x; 1.0555x over previous
//
#include <hip/hip_runtime.h>

// StochasticPool2D eval-mode: out = sum(w^2)/sum(w) over non-overlapping 2x2
// windows of relu(x); windows summing to 0 produce 0.
// x: [64, 256, 112, 112] f32  ->  out: [64, 256, 56, 56] f32
//
// Memory-bound: 822 MB read + 205 MB write, zero reuse.
// R2: same as R1 plan, but use clang ext_vector_type for the nontemporal
// builtins (HIP_vector_type float4 is a class -> rejected by the builtin).

#define W_IN   112
#define WO     56
#define HO     56
#define WP     28          // float4-groups per output row (4 input cols each)
#define PLANE  (112 * 112) // input elems per (b,c) plane
#define OPLANE (56 * 56)   // output elems per (b,c) plane

typedef float v4f __attribute__((ext_vector_type(4)));
typedef float v2f __attribute__((ext_vector_type(2)));

__device__ __forceinline__ void pool_addr(unsigned int p, unsigned int& ibase,
                                          unsigned int& obase) {
    unsigned int wp   = p % WP;
    unsigned int rest = p / WP;
    unsigned int ho   = rest % HO;
    unsigned int bc   = rest / HO;
    ibase = bc * PLANE + (2u * ho) * W_IN + wp * 4u;
    obase = bc * OPLANE + ho * WO + wp * 2u;
}

__device__ __forceinline__ v2f pool_compute(v4f r0, v4f r1) {
    float a0 = fmaxf(r0.x, 0.f), a1 = fmaxf(r0.y, 0.f);
    float a2 = fmaxf(r0.z, 0.f), a3 = fmaxf(r0.w, 0.f);
    float b0 = fmaxf(r1.x, 0.f), b1 = fmaxf(r1.y, 0.f);
    float b2 = fmaxf(r1.z, 0.f), b3 = fmaxf(r1.w, 0.f);
    float s0 = (a0 + a1) + (b0 + b1);
    float q0 = (a0 * a0 + a1 * a1) + (b0 * b0 + b1 * b1);
    float s1 = (a2 + a3) + (b2 + b3);
    float q1 = (a2 * a2 + a3 * a3) + (b2 * b2 + b3 * b3);
    v2f o;
    o.x = (s0 > 0.f) ? (q0 / s0) : 0.f;
    o.y = (s1 > 0.f) ? (q1 / s1) : 0.f;
    return o;
}

__global__ __launch_bounds__(256) void stoch_pool2d_kernel(
    const float* __restrict__ in, float* __restrict__ out, unsigned int npairs) {
    unsigned int stride = gridDim.x * blockDim.x;
    unsigned int p = blockIdx.x * blockDim.x + threadIdx.x;

    // Unrolled-by-4 main loop: issue all 8 loads before any compute.
    for (; p + 3u * stride < npairs; p += 4u * stride) {
        unsigned int ib0, ob0, ib1, ob1, ib2, ob2, ib3, ob3;
        pool_addr(p,               ib0, ob0);
        pool_addr(p + stride,      ib1, ob1);
        pool_addr(p + 2u * stride, ib2, ob2);
        pool_addr(p + 3u * stride, ib3, ob3);

        v4f r0_0 = __builtin_nontemporal_load(reinterpret_cast<const v4f*>(in + ib0));
        v4f r1_0 = __builtin_nontemporal_load(reinterpret_cast<const v4f*>(in + ib0 + W_IN));
        v4f r0_1 = __builtin_nontemporal_load(reinterpret_cast<const v4f*>(in + ib1));
        v4f r1_1 = __builtin_nontemporal_load(reinterpret_cast<const v4f*>(in + ib1 + W_IN));
        v4f r0_2 = __builtin_nontemporal_load(reinterpret_cast<const v4f*>(in + ib2));
        v4f r1_2 = __builtin_nontemporal_load(reinterpret_cast<const v4f*>(in + ib2 + W_IN));
        v4f r0_3 = __builtin_nontemporal_load(reinterpret_cast<const v4f*>(in + ib3));
        v4f r1_3 = __builtin_nontemporal_load(reinterpret_cast<const v4f*>(in + ib3 + W_IN));

        __builtin_nontemporal_store(pool_compute(r0_0, r1_0), reinterpret_cast<v2f*>(out + ob0));
        __builtin_nontemporal_store(pool_compute(r0_1, r1_1), reinterpret_cast<v2f*>(out + ob1));
        __builtin_nontemporal_store(pool_compute(r0_2, r1_2), reinterpret_cast<v2f*>(out + ob2));
        __builtin_nontemporal_store(pool_compute(r0_3, r1_3), reinterpret_cast<v2f*>(out + ob3));
    }
    // Tail
    for (; p < npairs; p += stride) {
        unsigned int ib, ob;
        pool_addr(p, ib, ob);
        v4f r0 = __builtin_nontemporal_load(reinterpret_cast<const v4f*>(in + ib));
        v4f r1 = __builtin_nontemporal_load(reinterpret_cast<const v4f*>(in + ib + W_IN));
        __builtin_nontemporal_store(pool_compute(r0, r1), reinterpret_cast<v2f*>(out + ob));
    }
}

extern "C" void kernel_launch(void* const* d_in, const int* in_sizes, int n_in,
                              void* d_out, int out_size, void* d_ws, size_t ws_size,
                              hipStream_t stream) {
    const float* x = (const float*)d_in[0];
    float* out = (float*)d_out;

    unsigned int npairs = (unsigned int)((long long)in_sizes[0] / 8);

    const int block = 256;
    const int grid = 2048;  // 256 CUs * 8 blocks/CU; 49 pairs/thread
    stoch_pool2d_kernel<<<grid, block, 0, stream>>>(x, out, npairs);
}

// Round 4
// 186.743 us; speedup vs baseline: 1.1607x; 1.0996x over previous
//
#include <hip/hip_runtime.h>

// StochasticPool2D eval-mode: out = sum(w^2)/sum(w) over non-overlapping 2x2
// windows of relu(x); windows summing to 0 produce 0.
// x: [64, 256, 112, 112] f32  ->  out: [64, 256, 56, 56] f32
//
// R3 redesign: previous per-thread row-pair loads made each wave-load a
// 448B-used/448B-skipped comb (rows are 448 B = 3.5 cachelines), fragmenting
// requests and (with NT) double-fetching the half-shared boundary line.
// Now each block stages a fully CONTIGUOUS 28672 B chunk (64 input rows) to
// LDS -- every wave load instr covers 1024 B dense & aligned -- then re-pairs
// rows out of LDS and writes the contiguous 7168 B output chunk.
//   1,835,008 global rows / 64 = 28672 chunks exactly; pairs never straddle
//   chunk or plane boundaries (64 and 112 both even).

typedef float v4f __attribute__((ext_vector_type(4)));
typedef float v2f __attribute__((ext_vector_type(2)));

#define NCHUNK 28672u
#define CH_IN  7168u   // f32 per input chunk  (64 rows x 112)
#define CH_OUT 1792u   // f32 per output chunk (32 rows x 56)

__global__ __launch_bounds__(256) void stoch_pool2d_kernel(
    const float* __restrict__ in, float* __restrict__ out) {
    __shared__ float lds[CH_IN];          // 28 KB -> 5 blocks/CU
    const unsigned int t = threadIdx.x;

    for (unsigned int c = blockIdx.x; c < NCHUNK; c += gridDim.x) {
        const v4f* src = reinterpret_cast<const v4f*>(in + (size_t)c * CH_IN);

        // Stage: 7 x 16B per thread, all loads issued before any LDS write.
        v4f r[7];
#pragma unroll
        for (int i = 0; i < 7; ++i)
            r[i] = __builtin_nontemporal_load(src + (i * 256u + t));
#pragma unroll
        for (int i = 0; i < 7; ++i)
            reinterpret_cast<v4f*>(lds)[i * 256u + t] = r[i];
        __syncthreads();

        // Compute: output element o pairs LDS rows 2*orow and 2*orow+1.
        float* dst = out + (size_t)c * CH_OUT;
        const v2f* l2 = reinterpret_cast<const v2f*>(lds);  // f2 row stride 56
#pragma unroll
        for (int i = 0; i < 7; ++i) {
            unsigned int o    = i * 256u + t;
            unsigned int orow = o / 56u;
            unsigned int ocol = o - orow * 56u;
            v2f top = l2[(2u * orow)      * 56u + ocol];
            v2f bot = l2[(2u * orow + 1u) * 56u + ocol];

            float a0 = fmaxf(top.x, 0.f), a1 = fmaxf(top.y, 0.f);
            float b0 = fmaxf(bot.x, 0.f), b1 = fmaxf(bot.y, 0.f);
            float s = (a0 + a1) + (b0 + b1);
            float q = (a0 * a0 + a1 * a1) + (b0 * b0 + b1 * b1);
            // v_rcp_f32 (~1 ulp) instead of full-precision divide; s==0
            // windows select 0 explicitly so the inf path is never stored.
            float v = (s > 0.f) ? q * __builtin_amdgcn_rcpf(s) : 0.f;
            __builtin_nontemporal_store(v, dst + o);
        }
        __syncthreads();  // protect LDS reuse next iteration
    }
}

extern "C" void kernel_launch(void* const* d_in, const int* in_sizes, int n_in,
                              void* d_out, int out_size, void* d_ws, size_t ws_size,
                              hipStream_t stream) {
    const float* x = (const float*)d_in[0];
    float* out = (float*)d_out;

    const int block = 256;
    const int grid = 2560;  // 5 blocks/CU resident (LDS-bound) x 2 rounds
    stoch_pool2d_kernel<<<grid, block, 0, stream>>>(x, out);
}

// Round 5
// 183.644 us; speedup vs baseline: 1.1803x; 1.0169x over previous
//
#include <hip/hip_runtime.h>

// StochasticPool2D eval-mode: out = sum(w^2)/sum(w) over non-overlapping 2x2
// windows of relu(x); windows summing to 0 produce 0.
// x: [64, 256, 112, 112] f32  ->  out: [64, 256, 56, 56] f32
//
// R4: chunked LDS scheme from R3 (dense contiguous 28 KB chunks) plus:
//  - software pipeline: prefetch next chunk into regs before the barrier, so
//    reads stay in flight during the compute+store phase (the read bubble).
//  - v4f output path: 4 ds_read_b128 -> 4 windows -> 1 nontemporal dwordx4
//    store per thread-iter (was 14 ds_read_b64 + 7 scalar stores).
//  - grid 2048: 28672 chunks / 2048 = exactly 14 per block.

typedef float v4f __attribute__((ext_vector_type(4)));

#define NCHUNK 28672u
#define CH_IN  7168u   // f32 per input chunk  (64 rows x 112)
#define CH_OUT 1792u   // f32 per output chunk (32 rows x 56)
#define GRID   2048u
#define ITERS  14u     // NCHUNK / GRID, exact

__device__ __forceinline__ float pool1(float x0, float x1, float y0, float y1) {
    float a0 = fmaxf(x0, 0.f), a1 = fmaxf(x1, 0.f);
    float b0 = fmaxf(y0, 0.f), b1 = fmaxf(y1, 0.f);
    float s = (a0 + a1) + (b0 + b1);
    float q = (a0 * a0 + a1 * a1) + (b0 * b0 + b1 * b1);
    return (s > 0.f) ? q * __builtin_amdgcn_rcpf(s) : 0.f;
}

__global__ __launch_bounds__(256) void stoch_pool2d_kernel(
    const float* __restrict__ in, float* __restrict__ out) {
    __shared__ float lds[CH_IN];          // 28 KB -> 5 blocks/CU
    const unsigned int t = threadIdx.x;

    unsigned int c = blockIdx.x;

    // Prologue: load first chunk into registers.
    v4f r[7];
    {
        const v4f* src = reinterpret_cast<const v4f*>(in + (size_t)c * CH_IN);
#pragma unroll
        for (int i = 0; i < 7; ++i)
            r[i] = __builtin_nontemporal_load(src + (i * 256u + t));
    }

    for (unsigned int it = 0; it < ITERS; ++it) {
        // Drain regs -> LDS (compiler waits vmcnt per-use here).
#pragma unroll
        for (int i = 0; i < 7; ++i)
            reinterpret_cast<v4f*>(lds)[i * 256u + t] = r[i];

        // Prefetch next chunk into regs BEFORE the barrier: these loads stay
        // in flight across the barrier and the whole compute phase.
        v4f nxt[7];
        if (it + 1u < ITERS) {
            const v4f* src =
                reinterpret_cast<const v4f*>(in + (size_t)(c + GRID) * CH_IN);
#pragma unroll
            for (int i = 0; i < 7; ++i)
                nxt[i] = __builtin_nontemporal_load(src + (i * 256u + t));
        }
        __syncthreads();

        // Compute: each thread-iter builds one output v4f (4 windows).
        // 448 output v4f per chunk: iter0 all 256 threads, iter1 t<192
        // (wave 3 fully idle -> no intra-wave divergence).
        float* dst = out + (size_t)c * CH_OUT;
        const v4f* l4 = reinterpret_cast<const v4f*>(lds);
#pragma unroll
        for (unsigned int i = 0; i < 2; ++i) {
            unsigned int o4 = i * 256u + t;
            if (o4 < 448u) {
                unsigned int orow = o4 / 14u;          // output row in chunk
                unsigned int oc4  = o4 - orow * 14u;   // v4f col in out row
                unsigned int base = orow * 56u + oc4 * 2u;  // v4f idx, top row
                v4f t0 = l4[base];
                v4f t1 = l4[base + 1u];
                v4f b0 = l4[base + 28u];               // +112 f32 = next row
                v4f b1 = l4[base + 29u];
                v4f v;
                v.x = pool1(t0.x, t0.y, b0.x, b0.y);
                v.y = pool1(t0.z, t0.w, b0.z, b0.w);
                v.z = pool1(t1.x, t1.y, b1.x, b1.y);
                v.w = pool1(t1.z, t1.w, b1.z, b1.w);
                __builtin_nontemporal_store(v, reinterpret_cast<v4f*>(dst) + o4);
            }
        }
        __syncthreads();  // protect LDS overwrite next iteration

#pragma unroll
        for (int i = 0; i < 7; ++i) r[i] = nxt[i];
        c += GRID;
    }
}

extern "C" void kernel_launch(void* const* d_in, const int* in_sizes, int n_in,
                              void* d_out, int out_size, void* d_ws, size_t ws_size,
                              hipStream_t stream) {
    const float* x = (const float*)d_in[0];
    float* out = (float*)d_out;

    stoch_pool2d_kernel<<<GRID, 256, 0, stream>>>(x, out);
}